// Round 5
// baseline (1459.233 us; speedup 1.0000x reference)
//
#include <hip/hip_runtime.h>
#include <stdint.h>

#define EPS 1e-5f

typedef __attribute__((ext_vector_type(4))) float f32x4;
typedef __attribute__((ext_vector_type(8))) __bf16 bf16x8;

__device__ __forceinline__ void gl_lds16(const void* g, void* l) {
    __builtin_amdgcn_global_load_lds(
        (const __attribute__((address_space(1))) void*)g,
        (__attribute__((address_space(3))) void*)l, 16, 0, 0);
}

__device__ __forceinline__ unsigned short f2bf(float f) {
    unsigned u = __builtin_bit_cast(unsigned, f);
    unsigned r = (u + 0x7FFFu + ((u >> 16) & 1u)) >> 16;   // RNE
    return (unsigned short)r;
}
__device__ __forceinline__ float bf2f(unsigned short h) {
    unsigned u = ((unsigned)h) << 16;
    return __builtin_bit_cast(float, u);
}

__device__ __forceinline__ uint4 expand8(unsigned int bt) {
    uint4 val;
    val.x = ((bt & 1u) ? 0x3F80u : 0u)  | ((bt & 2u) ? 0x3F800000u : 0u);
    val.y = ((bt & 4u) ? 0x3F80u : 0u)  | ((bt & 8u) ? 0x3F800000u : 0u);
    val.z = ((bt & 16u) ? 0x3F80u : 0u) | ((bt & 32u) ? 0x3F800000u : 0u);
    val.w = ((bt & 64u) ? 0x3F80u : 0u) | ((bt & 128u) ? 0x3F800000u : 0u);
    return val;
}

// ---------------- workspace layout (bytes) ----------------
#define OFF_W2S   0ULL                         // [3][9][128][64] bf16   = 442368
#define OFF_W3S   442368ULL                    // [3][18][256][64] bf16  = 1769472
#define OFF_FCS   2211840ULL                   // [3][256][512][64] bf16 = 50331648
#define OFF_S1M   52543488ULL                  // [8][128][1024] u64     = 8388608
#define OFF_S2PM  60932096ULL                  // [8][128][256][2] u64   = 4194304
#define OFF_S3    65126400ULL                  // [8][128][16384] bf16   = 33554432
#define OFF_PRE4P 98680832ULL                  // [8][1024][512] f32     = 16777216
#define OFF_FEAT  115458048ULL                 // [128][512] f32         = 262144
#define OFF_PN    115720192ULL                 // [10][512] f32          = 20480

// ---------------- weight repack + 3-way bf16 split (hi/mid/lo) ----------------
__global__ void repack_w2s(const float* __restrict__ w2, unsigned short* __restrict__ out) {
    int i = blockIdx.x * 256 + threadIdx.x;   // 73728
    if (i >= 73728) return;
    int oc = i / 576, rem = i % 576;
    int ic = rem / 9, tap = rem % 9;
    float w = w2[i];
    unsigned short hi = f2bf(w);  float r1 = w - bf2f(hi);
    unsigned short md = f2bf(r1); float r2 = r1 - bf2f(md);
    unsigned short lo = f2bf(r2);
    size_t base = ((size_t)(tap * 128 + oc)) * 64 + (((ic >> 3) ^ (oc & 7)) << 3) + (ic & 7);
    out[base] = hi; out[base + 73728] = md; out[base + 147456] = lo;
}
__global__ void repack_w3s(const float* __restrict__ w3, unsigned short* __restrict__ out) {
    int i = blockIdx.x * 256 + threadIdx.x;   // 294912
    if (i >= 294912) return;
    int oc = i / 1152, rem = i % 1152;
    int ic = rem / 9, tap = rem % 9;
    float w = w3[i];
    unsigned short hi = f2bf(w);  float r1 = w - bf2f(hi);
    unsigned short md = f2bf(r1); float r2 = r1 - bf2f(md);
    unsigned short lo = f2bf(r2);
    int cc = tap * 2 + (ic >> 6), icl = ic & 63;
    size_t base = ((size_t)(cc * 256 + oc)) * 64 + (((icl >> 3) ^ (oc & 7)) << 3) + (icl & 7);
    out[base] = hi; out[base + 294912] = md; out[base + 589824] = lo;
}
__global__ void repack_fcs(const float* __restrict__ fw, unsigned short* __restrict__ out) {
    int i = blockIdx.x * 256 + threadIdx.x;   // 8388608
    if (i >= 8388608) return;
    int f = i >> 14, d = i & 16383;
    float w = fw[i];
    unsigned short hi = f2bf(w);  float r1 = w - bf2f(hi);
    unsigned short md = f2bf(r1); float r2 = r1 - bf2f(md);
    unsigned short lo = f2bf(r2);
    int cc = d >> 6, kl = d & 63;
    size_t base = (((size_t)cc << 9) + f) * 64 + (((kl >> 3) ^ (f & 7)) << 3) + (kl & 7);
    out[base] = hi; out[base + 8388608] = md; out[base + 16777216] = lo;
}

// ---------------- conv1 + BN + LIF via LDS halo tile ----------------
__global__ __launch_bounds__(256) void conv1_lif_pack(
    const float* __restrict__ x, const float* __restrict__ w1,
    const float* __restrict__ g1, const float* __restrict__ b1,
    const float* __restrict__ m1, const float* __restrict__ var1,
    unsigned long long* __restrict__ s1m)
{
    __shared__ float xt[3][3][40];
    int blk = blockIdx.x;            // 128*32
    int b = blk >> 5, y = blk & 31;
    int tid = threadIdx.x;
    int w = tid >> 6, lane = tid & 63;

    float wr[27];
#pragma unroll
    for (int j = 0; j < 27; ++j) wr[j] = w1[lane * 27 + j];
    float scale = g1[lane] / sqrtf(var1[lane] + EPS);
    float bias  = b1[lane] - m1[lane] * scale;

    float v[8];
#pragma unroll
    for (int p = 0; p < 8; ++p) v[p] = 0.f;

    for (int t = 0; t < 8; ++t) {
        __syncthreads();
        const float* xb = x + ((size_t)(t * 128 + b)) * 3072;
        for (int i = tid; i < 360; i += 256) {
            int ic = i / 120, rem = i % 120, dr = rem / 40, col = rem % 40;
            int yy = y + dr - 1, xx = col - 4;
            float val = 0.f;
            if (yy >= 0 && yy < 32 && xx >= 0 && xx < 32)
                val = xb[ic * 1024 + yy * 32 + xx];
            xt[ic][dr][col] = val;
        }
        __syncthreads();

        float acc[8];
#pragma unroll
        for (int p = 0; p < 8; ++p) acc[p] = 0.f;
#pragma unroll
        for (int ic = 0; ic < 3; ++ic)
#pragma unroll
        for (int dr = 0; dr < 3; ++dr) {
            const float* row = &xt[ic][dr][w * 8];
            float bf[16];
            *(float4*)&bf[0]  = *(const float4*)&row[0];
            *(float4*)&bf[4]  = *(const float4*)&row[4];
            *(float4*)&bf[8]  = *(const float4*)&row[8];
            *(float4*)&bf[12] = *(const float4*)&row[12];
#pragma unroll
            for (int p = 0; p < 8; ++p)
#pragma unroll
                for (int dxm = 0; dxm < 3; ++dxm)
                    acc[p] += bf[p + dxm + 3] * wr[ic * 9 + dr * 3 + dxm];
        }
        size_t base = ((size_t)t * 128 + b) * 1024 + y * 32 + w * 8;
#pragma unroll
        for (int p = 0; p < 8; ++p) {
            float pre = acc[p] * scale + bias;
            v[p] = v[p] + (pre - v[p]) * 0.5f;
            bool s = (v[p] >= 1.0f);
            unsigned long long mk = __ballot(s);
            if (s) v[p] = 0.f;
            if (lane == 0) s1m[base + p] = mk;
        }
    }
}

// ---------------- conv2 MFMA: whole-halo A expansion + dbuf-prefetched B ----------------
// launch_bounds(256) only: LDS (63KB) bounds occupancy at 2 blocks/CU; free VGPR
// budget avoids the round-4 scratch spills (FETCH 270MB -> ~10MB).
__global__ __launch_bounds__(256) void conv2_mfma(
    const unsigned long long* __restrict__ s1m,   // [8][128][1024]
    const unsigned short* __restrict__ w2s,
    const float* __restrict__ g, const float* __restrict__ bb,
    const float* __restrict__ mm, const float* __restrict__ vv,
    unsigned long long* __restrict__ s2pm)        // [8][128][256][2]
{
    __shared__ unsigned long long mt[2][6][34];    // 3264 B
    __shared__ unsigned short Aexp[204 * 64];      // 26112 B
    __shared__ unsigned short Bt[2][8192];         // 32768 B
    __shared__ unsigned short pm16[2][16][8];      // 512 B

    int tid = threadIdx.x;
    int m0 = blockIdx.x << 7;
    int b = m0 >> 10;
    int pix0 = m0 & 1023;
    int y0 = pix0 >> 5;

    int w = tid >> 6, lane = tid & 63;
    int wm = w & 1, wn = w >> 1;
    int q = lane >> 4, r = lane & 15;
    int swr = r & 7;

    int yloc[4], xloc[4];
#pragma unroll
    for (int i = 0; i < 4; ++i) {
        int mrow = wm * 64 + i * 16 + r;
        yloc[i] = mrow >> 5; xloc[i] = mrow & 31;
    }

    float scl[4], bia[4];
#pragma unroll
    for (int j = 0; j < 4; ++j) {
        int oc = wn * 64 + j * 16 + r;
        float s0 = g[oc] / sqrtf(vv[oc] + EPS);
        scl[j] = s0;
        bia[j] = bb[oc] - mm[oc] * s0;
    }

    float vr[4][4][4];
#pragma unroll
    for (int i = 0; i < 4; ++i)
#pragma unroll
        for (int j = 0; j < 4; ++j)
#pragma unroll
            for (int k = 0; k < 4; ++k) vr[i][j][k] = 0.f;

    const char* w2sb = (const char*)w2s;

    // ---- prologue: stage mt[0], prefetch B(tap0,s0) -> Bt[0]
    for (int i = tid; i < 204; i += 256) {
        int ly = i / 34, lx = i % 34;
        int yy = y0 + ly - 1, xx = lx - 1;
        unsigned long long mv = 0ULL;
        if (yy >= 0 && yy < 32 && xx >= 0 && xx < 32)
            mv = s1m[(b << 10) + (yy << 5) + xx];
        mt[0][ly][lx] = mv;
    }
    {
        const char* gb = w2sb + (w << 12) + (lane << 4);
        char* lb = (char*)Bt[0] + (w << 12);
#pragma unroll
        for (int p = 0; p < 4; ++p) gl_lds16(gb + (p << 10), lb + (p << 10));
    }
    __syncthreads();

    int it = 0;
    for (int t = 0; t < 8; ++t) {
        // build Aexp from mt[t&1]; stage mt[(t+1)&1]
        {
            const unsigned long long* mtc = &mt[t & 1][0][0];
            for (int u = tid; u < 408; u += 256) {
                int p = u >> 1, hc = u & 1;
                unsigned long long mk = mtc[p];
                unsigned int w32 = (unsigned int)(mk >> (hc << 5));
#pragma unroll
                for (int c4 = 0; c4 < 4; ++c4) {
                    int c = (hc << 2) + c4;
                    *(uint4*)((char*)Aexp + p * 128 + ((c ^ (p & 7)) << 4)) =
                        expand8(w32 >> (c4 << 3));
                }
            }
        }
        if (t < 7) {
            for (int i = tid; i < 204; i += 256) {
                int ly = i / 34, lx = i % 34;
                int yy = y0 + ly - 1, xx = lx - 1;
                unsigned long long mv = 0ULL;
                if (yy >= 0 && yy < 32 && xx >= 0 && xx < 32)
                    mv = s1m[(size_t)(t + 1) * 131072 + (b << 10) + (yy << 5) + xx];
                mt[(t + 1) & 1][ly][lx] = mv;
            }
        }
        __syncthreads();

        f32x4 acc[4][4];
#pragma unroll
        for (int i = 0; i < 4; ++i)
#pragma unroll
            for (int j = 0; j < 4; ++j) acc[i][j] = (f32x4){0.f, 0.f, 0.f, 0.f};

        for (int tap = 0; tap < 9; ++tap) {
            int dy = tap / 3, dx = tap - dy * 3;
#pragma unroll
            for (int s = 0; s < 3; ++s) {
                {   // prefetch next iter's B
                    int s2 = s + 1, tap2 = tap;
                    if (s2 == 3) { s2 = 0; tap2 = tap + 1; if (tap2 == 9) tap2 = 0; }
                    const char* gb = w2sb + s2 * 147456 + tap2 * 16384 + (w << 12) + (lane << 4);
                    char* lb = (char*)Bt[(it + 1) & 1] + (w << 12);
#pragma unroll
                    for (int p = 0; p < 4; ++p) gl_lds16(gb + (p << 10), lb + (p << 10));
                }
                const char* Bc = (const char*)Bt[it & 1];
#pragma unroll
                for (int ks = 0; ks < 2; ++ks) {
                    bf16x8 af[4];
#pragma unroll
                    for (int i = 0; i < 4; ++i) {
                        int p = (yloc[i] + dy) * 34 + xloc[i] + dx;
                        af[i] = *(const bf16x8*)((const char*)Aexp + p * 128 +
                                 ((((ks << 2) + q) ^ (p & 7)) << 4));
                    }
                    bf16x8 bfr[4];
#pragma unroll
                    for (int j = 0; j < 4; ++j)
                        bfr[j] = *(const bf16x8*)(Bc + (wn * 64 + j * 16 + r) * 128 + ((((ks << 2) + q) ^ swr) << 4));
#pragma unroll
                    for (int i = 0; i < 4; ++i)
#pragma unroll
                        for (int j = 0; j < 4; ++j)
                            acc[i][j] = __builtin_amdgcn_mfma_f32_16x16x32_bf16(af[i], bfr[j], acc[i][j], 0, 0, 0);
                }
                __syncthreads();
                ++it;
            }
        }

        // epilogue: BN + LIF (v in regs) + 2x2 pool + bitpack
        unsigned long long S = 0ULL;
#pragma unroll
        for (int i = 0; i < 4; ++i)
#pragma unroll
            for (int j = 0; j < 4; ++j)
#pragma unroll
                for (int reg = 0; reg < 4; ++reg) {
                    float pre = acc[i][j][reg] * scl[j] + bia[j];
                    float vo = vr[i][j][reg];
                    vo = vo + (pre - vo) * 0.5f;
                    bool sp = (vo >= 1.0f);
                    vr[i][j][reg] = sp ? 0.f : vo;
                    if (sp) S |= 1ULL << (i * 16 + j * 4 + reg);
                }
#pragma unroll
        for (int b1 = 0; b1 < 2; ++b1)
#pragma unroll
            for (int u = 0; u < 2; ++u)
#pragma unroll
                for (int j = 0; j < 4; ++j) {
                    int k0 = b1 * 16 + j * 4 + 2 * u;
                    bool sp = (((S >> k0) | (S >> (k0 + 1)) | (S >> (k0 + 32)) | (S >> (k0 + 33))) & 1ULL) != 0;
                    unsigned long long mk = __ballot(sp);
                    if (r == 0)
                        pm16[wm][b1 * 8 + (q << 1) + u][wn * 4 + j] = (unsigned short)(mk >> (q << 4));
                }
        __syncthreads();
        if (tid < 64) {
            int py = tid >> 5, px = (tid >> 1) & 15, h = tid & 1;
            unsigned long long vmk = *(unsigned long long*)&pm16[py][px][h << 2];
            s2pm[(size_t)t * 65536 + ((size_t)(b << 8) + ((y0 >> 1) + py) * 16 + px) * 2 + h] = vmk;
        }
    }
}

// ---------------- conv3 MFMA: halo expansion per ic-half + dbuf-prefetched B ----------------
__global__ __launch_bounds__(256) void conv3_mfma(
    const unsigned long long* __restrict__ s2pm,  // [8][128][256][2]
    const unsigned short* __restrict__ w3s,
    const float* __restrict__ g, const float* __restrict__ bb,
    const float* __restrict__ mm, const float* __restrict__ vv,
    unsigned short* __restrict__ s3)              // [8][128][16384] bf16, swizzled
{
    __shared__ unsigned long long mt3[2][10][18][2];  // 5760 B
    __shared__ unsigned short Aexp[180 * 64];         // 23040 B
    __shared__ unsigned short Bt[2][8192];            // 32768 B

    int tid = threadIdx.x;
    int m0 = blockIdx.x << 7;
    int n0 = blockIdx.y << 7;
    int b = m0 >> 8;
    int pix0 = m0 & 255;
    int y0 = pix0 >> 4;     // 0 or 8

    int w = tid >> 6, lane = tid & 63;
    int wm = w & 1, wn = w >> 1;
    int q = lane >> 4, r = lane & 15;
    int swr = r & 7;

    int yloc[4], xloc[4];
#pragma unroll
    for (int i = 0; i < 4; ++i) {
        int mrow = wm * 64 + i * 16 + r;
        yloc[i] = mrow >> 4; xloc[i] = mrow & 15;
    }

    float scl[4], bia[4];
#pragma unroll
    for (int j = 0; j < 4; ++j) {
        int oc = n0 + wn * 64 + j * 16 + r;
        float s0 = g[oc] / sqrtf(vv[oc] + EPS);
        scl[j] = s0;
        bia[j] = bb[oc] - mm[oc] * s0;
    }

    float vr[4][4][4];
#pragma unroll
    for (int i = 0; i < 4; ++i)
#pragma unroll
        for (int j = 0; j < 4; ++j)
#pragma unroll
            for (int k = 0; k < 4; ++k) vr[i][j][k] = 0.f;

    const char* w3sb = (const char*)w3s;
    int bsw = b & 7;

    // ---- prologue: stage mt3[0], prefetch B(cc=0,s=0) -> Bt[0]
    for (int i = tid; i < 180; i += 256) {
        int ly = i / 18, lx = i % 18;
        int yy = y0 + ly - 1, xx = lx - 1;
        unsigned long long v0 = 0ULL, v1 = 0ULL;
        if (yy >= 0 && yy < 16 && xx >= 0 && xx < 16) {
            const unsigned long long* p = &s2pm[((size_t)(b << 8) + (yy << 4) + xx) * 2];
            v0 = p[0]; v1 = p[1];
        }
        mt3[0][ly][lx][0] = v0; mt3[0][ly][lx][1] = v1;
    }
    {
        const char* gb = w3sb + n0 * 128 + (w << 12) + (lane << 4);
        char* lb = (char*)Bt[0] + (w << 12);
#pragma unroll
        for (int p = 0; p < 4; ++p) gl_lds16(gb + (p << 10), lb + (p << 10));
    }
    __syncthreads();

    int it = 0;
    for (int t = 0; t < 8; ++t) {
        // build Aexp (h=0); stage mt3 for t+1
        {
            const unsigned long long* mtc = &mt3[t & 1][0][0][0];
            for (int u = tid; u < 360; u += 256) {
                int p = u >> 1, hc = u & 1;
                unsigned long long mk = mtc[p * 2];    // h = 0
                unsigned int w32 = (unsigned int)(mk >> (hc << 5));
#pragma unroll
                for (int c4 = 0; c4 < 4; ++c4) {
                    int c = (hc << 2) + c4;
                    *(uint4*)((char*)Aexp + p * 128 + ((c ^ (p & 7)) << 4)) =
                        expand8(w32 >> (c4 << 3));
                }
            }
        }
        if (t < 7) {
            for (int i = tid; i < 180; i += 256) {
                int ly = i / 18, lx = i % 18;
                int yy = y0 + ly - 1, xx = lx - 1;
                unsigned long long v0 = 0ULL, v1 = 0ULL;
                if (yy >= 0 && yy < 16 && xx >= 0 && xx < 16) {
                    const unsigned long long* p = &s2pm[(size_t)(t + 1) * 65536 + ((size_t)(b << 8) + (yy << 4) + xx) * 2];
                    v0 = p[0]; v1 = p[1];
                }
                mt3[(t + 1) & 1][ly][lx][0] = v0; mt3[(t + 1) & 1][ly][lx][1] = v1;
            }
        }
        __syncthreads();

        f32x4 acc[4][4];
#pragma unroll
        for (int i = 0; i < 4; ++i)
#pragma unroll
            for (int j = 0; j < 4; ++j) acc[i][j] = (f32x4){0.f, 0.f, 0.f, 0.f};

        for (int h = 0; h < 2; ++h) {
            for (int tap = 0; tap < 9; ++tap) {
                int dy = tap / 3, dx = tap - dy * 3;
                int cc = tap * 2 + h;
#pragma unroll
                for (int s = 0; s < 3; ++s) {
                    {   // prefetch next iter's B
                        int s2 = s + 1, cc2 = cc;
                        if (s2 == 3) {
                            s2 = 0; cc2 = cc + 2;
                            if (cc2 >= 18) cc2 = (h == 0) ? 1 : 0;
                        }
                        const char* gb = w3sb + s2 * 589824 + cc2 * 32768 + n0 * 128 + (w << 12) + (lane << 4);
                        char* lb = (char*)Bt[(it + 1) & 1] + (w << 12);
#pragma unroll
                        for (int p = 0; p < 4; ++p) gl_lds16(gb + (p << 10), lb + (p << 10));
                    }
                    const char* Bc = (const char*)Bt[it & 1];
#pragma unroll
                    for (int ks = 0; ks < 2; ++ks) {
                        bf16x8 af[4];
#pragma unroll
                        for (int i = 0; i < 4; ++i) {
                            int p = (yloc[i] + dy) * 18 + xloc[i] + dx;
                            af[i] = *(const bf16x8*)((const char*)Aexp + p * 128 +
                                     ((((ks << 2) + q) ^ (p & 7)) << 4));
                        }
                        bf16x8 bfr[4];
#pragma unroll
                        for (int j = 0; j < 4; ++j)
                            bfr[j] = *(const bf16x8*)(Bc + (wn * 64 + j * 16 + r) * 128 + ((((ks << 2) + q) ^ swr) << 4));
#pragma unroll
                        for (int i = 0; i < 4; ++i)
#pragma unroll
                            for (int j = 0; j < 4; ++j)
                                acc[i][j] = __builtin_amdgcn_mfma_f32_16x16x32_bf16(af[i], bfr[j], acc[i][j], 0, 0, 0);
                    }
                    __syncthreads();
                    ++it;
                }
            }
            if (h == 0) {   // rebuild Aexp for ic-half 1
                const unsigned long long* mtc = &mt3[t & 1][0][0][0];
                for (int u = tid; u < 360; u += 256) {
                    int p = u >> 1, hc = u & 1;
                    unsigned long long mk = mtc[p * 2 + 1];    // h = 1
                    unsigned int w32 = (unsigned int)(mk >> (hc << 5));
#pragma unroll
                    for (int c4 = 0; c4 < 4; ++c4) {
                        int c = (hc << 2) + c4;
                        *(uint4*)((char*)Aexp + p * 128 + ((c ^ (p & 7)) << 4)) =
                            expand8(w32 >> (c4 << 3));
                    }
                }
                __syncthreads();
            }
        }

        // epilogue: BN + LIF + pool -> bf16 spikes
        unsigned long long S = 0ULL;
#pragma unroll
        for (int i = 0; i < 4; ++i)
#pragma unroll
            for (int j = 0; j < 4; ++j)
#pragma unroll
                for (int reg = 0; reg < 4; ++reg) {
                    float pre = acc[i][j][reg] * scl[j] + bia[j];
                    float vo = vr[i][j][reg];
                    vo = vo + (pre - vo) * 0.5f;
                    bool sp = (vo >= 1.0f);
                    vr[i][j][reg] = sp ? 0.f : vo;
                    if (sp) S |= 1ULL << (i * 16 + j * 4 + reg);
                }
        unsigned short* s3t = s3 + (size_t)t * 2097152;
#pragma unroll
        for (int a2 = 0; a2 < 2; ++a2)
#pragma unroll
            for (int u = 0; u < 2; ++u)
#pragma unroll
                for (int j = 0; j < 4; ++j) {
                    int kA = 32 * a2 + j * 4 + 2 * u;
                    bool sp = (((S >> kA) | (S >> (kA + 1)) | (S >> (kA + 16)) | (S >> (kA + 17))) & 1ULL) != 0;
                    int oc = n0 + wn * 64 + j * 16 + r;
                    int y2 = (y0 >> 1) + wm * 2 + a2;
                    int x2 = (q << 1) + u;
                    s3t[(size_t)(b << 14) + oc * 64 + ((y2 ^ bsw) << 3) + x2] =
                        (unsigned short)(sp ? 0x3F80 : 0);
                }
    }
}

// ---------------- FC MFMA GEMM, split-K into 8 deterministic partials ----------------
__global__ __launch_bounds__(256, 2) void fc_mfma(
    const unsigned short* __restrict__ s3,    // [1024][16384] bf16, swizzled by (m&7)
    const unsigned short* __restrict__ fcs,
    float* __restrict__ pre4p)                // [8][1024][512]
{
    __shared__ unsigned short A[128 * 64];
    __shared__ unsigned short B[3 * 128 * 64];

    int tid = threadIdx.x;
    int m0 = blockIdx.x << 7;
    int n0 = blockIdx.y << 7;
    int kseg = blockIdx.z;
    int cc0 = kseg << 5;

    int w = tid >> 6, lane = tid & 63;
    int wm = w & 1, wn = w >> 1;
    int q = lane >> 4, r = lane & 15;
    int swr = r & 7;

    f32x4 acc[4][4];
#pragma unroll
    for (int i = 0; i < 4; ++i)
#pragma unroll
        for (int j = 0; j < 4; ++j) acc[i][j] = (f32x4){0.f, 0.f, 0.f, 0.f};

    const char* s3b = (const char*)s3;
    const char* fcsb = (const char*)fcs;

    for (int cc = cc0; cc < cc0 + 32; ++cc) {
        __syncthreads();
        {
            char* lb = (char*)A + (w << 12);
#pragma unroll
            for (int p = 0; p < 4; ++p)
                gl_lds16(s3b + (size_t)(m0 + w * 32 + p * 8 + (lane >> 3)) * 32768
                             + cc * 128 + ((lane & 7) << 4),
                         lb + (p << 10));
        }
        {
            const char* gb = fcsb + cc * 65536 + n0 * 128 + (w << 12) + (lane << 4);
            char* lb = (char*)B + (w << 12);
#pragma unroll
            for (int s = 0; s < 3; ++s)
#pragma unroll
                for (int p = 0; p < 4; ++p)
                    gl_lds16(gb + s * 16777216 + (p << 10), lb + s * 16384 + (p << 10));
        }
        __syncthreads();
#pragma unroll
        for (int ks = 0; ks < 2; ++ks) {
            bf16x8 af[4];
#pragma unroll
            for (int i = 0; i < 4; ++i)
                af[i] = *(const bf16x8*)((const char*)A + (wm * 64 + i * 16 + r) * 128 + ((((ks << 2) + q) ^ swr) << 4));
#pragma unroll
            for (int s = 0; s < 3; ++s) {
                bf16x8 bfr[4];
#pragma unroll
                for (int j = 0; j < 4; ++j)
                    bfr[j] = *(const bf16x8*)((const char*)B + s * 16384 + (wn * 64 + j * 16 + r) * 128 + ((((ks << 2) + q) ^ swr) << 4));
#pragma unroll
                for (int i = 0; i < 4; ++i)
#pragma unroll
                    for (int j = 0; j < 4; ++j)
                        acc[i][j] = __builtin_amdgcn_mfma_f32_16x16x32_bf16(af[i], bfr[j], acc[i][j], 0, 0, 0);
            }
        }
    }
#pragma unroll
    for (int i = 0; i < 4; ++i) {
#pragma unroll
        for (int j = 0; j < 4; ++j) {
            size_t base = ((size_t)kseg * 1024 + m0 + wm * 64 + i * 16 + (q << 2)) * 512
                        + n0 + wn * 64 + j * 16 + r;
#pragma unroll
            for (int reg = 0; reg < 4; ++reg)
                pre4p[base + (size_t)reg * 512] = acc[i][j][reg];
        }
    }
}

// ---------------- LIF over FC output (sum 8 partials deterministically) + mean ----------------
__global__ void lif4_mean(const float* __restrict__ P, float* __restrict__ feat) {
    int i = blockIdx.x * 256 + threadIdx.x;
    if (i >= 65536) return;
    int b = i >> 9, f = i & 511;
    float v = 0.f, sum = 0.f;
#pragma unroll
    for (int t = 0; t < 8; ++t) {
        float pre = 0.f;
#pragma unroll
        for (int s = 0; s < 8; ++s)
            pre += P[(size_t)s * 524288 + (size_t)(t * 128 + b) * 512 + f];
        v = v + (pre - v) * 0.5f;
        if (v >= 1.0f) { sum += 1.f; v = 0.f; }
    }
    feat[i] = sum * 0.125f;
}

__global__ void protos_norm(const float* __restrict__ P, float* __restrict__ pn) {
    int p = blockIdx.x;
    int lane = threadIdx.x;
    float ss = 0.f;
    for (int f = lane; f < 512; f += 64) { float x = P[p * 512 + f]; ss += x * x; }
#pragma unroll
    for (int o = 32; o > 0; o >>= 1) ss += __shfl_xor(ss, o);
    float inv = 1.f / fmaxf(sqrtf(ss), 1e-12f);
    for (int f = lane; f < 512; f += 64) pn[p * 512 + f] = P[p * 512 + f] * inv;
}

__global__ void final_logits(const float* __restrict__ feat, const float* __restrict__ pn,
                             float* __restrict__ out) {
    int b = blockIdx.x;
    int lane = threadIdx.x;
    float fr[8];
    float ss = 0.f;
#pragma unroll
    for (int j = 0; j < 8; ++j) { fr[j] = feat[b * 512 + j * 64 + lane]; ss += fr[j] * fr[j]; }
#pragma unroll
    for (int o = 32; o > 0; o >>= 1) ss += __shfl_xor(ss, o);
    float inv = 10.f / fmaxf(sqrtf(ss), 1e-12f);
    for (int p = 0; p < 10; ++p) {
        float d = 0.f;
#pragma unroll
        for (int j = 0; j < 8; ++j) d += fr[j] * pn[p * 512 + j * 64 + lane];
#pragma unroll
        for (int o = 32; o > 0; o >>= 1) d += __shfl_xor(d, o);
        if (lane == 0) out[b * 10 + p] = d * inv;
    }
}

extern "C" void kernel_launch(void* const* d_in, const int* in_sizes, int n_in,
                              void* d_out, int out_size, void* d_ws, size_t ws_size,
                              hipStream_t stream) {
    const float* x      = (const float*)d_in[0];
    const float* w1     = (const float*)d_in[1];
    const float* w2     = (const float*)d_in[2];
    const float* w3     = (const float*)d_in[3];
    const float* fc1    = (const float*)d_in[4];
    const float* protos = (const float*)d_in[5];
    const float* g1 = (const float*)d_in[6],  *b1 = (const float*)d_in[7];
    const float* m1 = (const float*)d_in[8],  *v1 = (const float*)d_in[9];
    const float* g2 = (const float*)d_in[10], *b2 = (const float*)d_in[11];
    const float* m2 = (const float*)d_in[12], *v2p = (const float*)d_in[13];
    const float* g3 = (const float*)d_in[14], *b3 = (const float*)d_in[15];
    const float* m3 = (const float*)d_in[16], *v3p = (const float*)d_in[17];

    char* ws = (char*)d_ws;
    unsigned short* w2s = (unsigned short*)(ws + OFF_W2S);
    unsigned short* w3s = (unsigned short*)(ws + OFF_W3S);
    unsigned short* fcs = (unsigned short*)(ws + OFF_FCS);
    unsigned long long* s1m  = (unsigned long long*)(ws + OFF_S1M);
    unsigned long long* s2pm = (unsigned long long*)(ws + OFF_S2PM);
    unsigned short* s3 = (unsigned short*)(ws + OFF_S3);
    float* pre4p = (float*)(ws + OFF_PRE4P);
    float* feat  = (float*)(ws + OFF_FEAT);
    float* pn    = (float*)(ws + OFF_PN);

    repack_w2s<<<288, 256, 0, stream>>>(w2, w2s);
    repack_w3s<<<1152, 256, 0, stream>>>(w3, w3s);
    repack_fcs<<<32768, 256, 0, stream>>>(fc1, fcs);

    conv1_lif_pack<<<4096, 256, 0, stream>>>(x, w1, g1, b1, m1, v1, s1m);
    conv2_mfma<<<1024, 256, 0, stream>>>(s1m, w2s, g2, b2, m2, v2p, s2pm);
    conv3_mfma<<<dim3(256, 2), 256, 0, stream>>>(s2pm, w3s, g3, b3, m3, v3p, s3);

    fc_mfma<<<dim3(8, 4, 8), 256, 0, stream>>>(s3, fcs, pre4p);
    lif4_mean<<<256, 256, 0, stream>>>(pre4p, feat);
    protos_norm<<<10, 64, 0, stream>>>(protos, pn);
    final_logits<<<128, 64, 0, stream>>>(feat, pn, (float*)d_out);
}

// Round 6
// 938.165 us; speedup vs baseline: 1.5554x; 1.5554x over previous
//
#include <hip/hip_runtime.h>
#include <stdint.h>

#define EPS 1e-5f

typedef __attribute__((ext_vector_type(4))) float f32x4;
typedef __attribute__((ext_vector_type(8))) __bf16 bf16x8;

__device__ __forceinline__ void gl_lds16(const void* g, void* l) {
    __builtin_amdgcn_global_load_lds(
        (const __attribute__((address_space(1))) void*)g,
        (__attribute__((address_space(3))) void*)l, 16, 0, 0);
}

__device__ __forceinline__ unsigned short f2bf(float f) {
    unsigned u = __builtin_bit_cast(unsigned, f);
    unsigned r = (u + 0x7FFFu + ((u >> 16) & 1u)) >> 16;   // RNE
    return (unsigned short)r;
}
__device__ __forceinline__ float bf2f(unsigned short h) {
    unsigned u = ((unsigned)h) << 16;
    return __builtin_bit_cast(float, u);
}

__device__ __forceinline__ uint4 expand8(unsigned int bt) {
    uint4 val;
    val.x = ((bt & 1u) ? 0x3F80u : 0u)  | ((bt & 2u) ? 0x3F800000u : 0u);
    val.y = ((bt & 4u) ? 0x3F80u : 0u)  | ((bt & 8u) ? 0x3F800000u : 0u);
    val.z = ((bt & 16u) ? 0x3F80u : 0u) | ((bt & 32u) ? 0x3F800000u : 0u);
    val.w = ((bt & 64u) ? 0x3F80u : 0u) | ((bt & 128u) ? 0x3F800000u : 0u);
    return val;
}

// ---------------- workspace layout (bytes) ----------------
#define OFF_W2S   0ULL                         // [3][9][128][64] bf16   = 442368
#define OFF_W3S   442368ULL                    // [3][18][256][64] bf16  = 1769472
#define OFF_FCS   2211840ULL                   // [3][256][512][64] bf16 = 50331648
#define OFF_S1M   52543488ULL                  // [8][128][1024] u64     = 8388608
#define OFF_S2PM  60932096ULL                  // [8][128][256][2] u64   = 4194304
#define OFF_S3    65126400ULL                  // [8][128][16384] bf16   = 33554432
#define OFF_PRE4P 98680832ULL                  // [8][1024][512] f32     = 16777216
#define OFF_FEAT  115458048ULL                 // [128][512] f32         = 262144
#define OFF_PN    115720192ULL                 // [10][512] f32          = 20480

// ---------------- weight repack + 3-way bf16 split (hi/mid/lo) ----------------
__global__ void repack_w2s(const float* __restrict__ w2, unsigned short* __restrict__ out) {
    int i = blockIdx.x * 256 + threadIdx.x;   // 73728
    if (i >= 73728) return;
    int oc = i / 576, rem = i % 576;
    int ic = rem / 9, tap = rem % 9;
    float w = w2[i];
    unsigned short hi = f2bf(w);  float r1 = w - bf2f(hi);
    unsigned short md = f2bf(r1); float r2 = r1 - bf2f(md);
    unsigned short lo = f2bf(r2);
    size_t base = ((size_t)(tap * 128 + oc)) * 64 + (((ic >> 3) ^ (oc & 7)) << 3) + (ic & 7);
    out[base] = hi; out[base + 73728] = md; out[base + 147456] = lo;
}
__global__ void repack_w3s(const float* __restrict__ w3, unsigned short* __restrict__ out) {
    int i = blockIdx.x * 256 + threadIdx.x;   // 294912
    if (i >= 294912) return;
    int oc = i / 1152, rem = i % 1152;
    int ic = rem / 9, tap = rem % 9;
    float w = w3[i];
    unsigned short hi = f2bf(w);  float r1 = w - bf2f(hi);
    unsigned short md = f2bf(r1); float r2 = r1 - bf2f(md);
    unsigned short lo = f2bf(r2);
    int cc = tap * 2 + (ic >> 6), icl = ic & 63;
    size_t base = ((size_t)(cc * 256 + oc)) * 64 + (((icl >> 3) ^ (oc & 7)) << 3) + (icl & 7);
    out[base] = hi; out[base + 294912] = md; out[base + 589824] = lo;
}
__global__ void repack_fcs(const float* __restrict__ fw, unsigned short* __restrict__ out) {
    int i = blockIdx.x * 256 + threadIdx.x;   // 8388608
    if (i >= 8388608) return;
    int f = i >> 14, d = i & 16383;
    float w = fw[i];
    unsigned short hi = f2bf(w);  float r1 = w - bf2f(hi);
    unsigned short md = f2bf(r1); float r2 = r1 - bf2f(md);
    unsigned short lo = f2bf(r2);
    int cc = d >> 6, kl = d & 63;
    size_t base = (((size_t)cc << 9) + f) * 64 + (((kl >> 3) ^ (f & 7)) << 3) + (kl & 7);
    out[base] = hi; out[base + 8388608] = md; out[base + 16777216] = lo;
}

// ---------------- conv1 + BN + LIF via LDS halo tile ----------------
__global__ __launch_bounds__(256) void conv1_lif_pack(
    const float* __restrict__ x, const float* __restrict__ w1,
    const float* __restrict__ g1, const float* __restrict__ b1,
    const float* __restrict__ m1, const float* __restrict__ var1,
    unsigned long long* __restrict__ s1m)
{
    __shared__ float xt[3][3][40];
    int blk = blockIdx.x;            // 128*32
    int b = blk >> 5, y = blk & 31;
    int tid = threadIdx.x;
    int w = tid >> 6, lane = tid & 63;

    float wr[27];
#pragma unroll
    for (int j = 0; j < 27; ++j) wr[j] = w1[lane * 27 + j];
    float scale = g1[lane] / sqrtf(var1[lane] + EPS);
    float bias  = b1[lane] - m1[lane] * scale;

    float v[8];
#pragma unroll
    for (int p = 0; p < 8; ++p) v[p] = 0.f;

    for (int t = 0; t < 8; ++t) {
        __syncthreads();
        const float* xb = x + ((size_t)(t * 128 + b)) * 3072;
        for (int i = tid; i < 360; i += 256) {
            int ic = i / 120, rem = i % 120, dr = rem / 40, col = rem % 40;
            int yy = y + dr - 1, xx = col - 4;
            float val = 0.f;
            if (yy >= 0 && yy < 32 && xx >= 0 && xx < 32)
                val = xb[ic * 1024 + yy * 32 + xx];
            xt[ic][dr][col] = val;
        }
        __syncthreads();

        float acc[8];
#pragma unroll
        for (int p = 0; p < 8; ++p) acc[p] = 0.f;
#pragma unroll
        for (int ic = 0; ic < 3; ++ic)
#pragma unroll
        for (int dr = 0; dr < 3; ++dr) {
            const float* row = &xt[ic][dr][w * 8];
            float bf[16];
            *(float4*)&bf[0]  = *(const float4*)&row[0];
            *(float4*)&bf[4]  = *(const float4*)&row[4];
            *(float4*)&bf[8]  = *(const float4*)&row[8];
            *(float4*)&bf[12] = *(const float4*)&row[12];
#pragma unroll
            for (int p = 0; p < 8; ++p)
#pragma unroll
                for (int dxm = 0; dxm < 3; ++dxm)
                    acc[p] += bf[p + dxm + 3] * wr[ic * 9 + dr * 3 + dxm];
        }
        size_t base = ((size_t)t * 128 + b) * 1024 + y * 32 + w * 8;
#pragma unroll
        for (int p = 0; p < 8; ++p) {
            float pre = acc[p] * scale + bias;
            v[p] = v[p] + (pre - v[p]) * 0.5f;
            bool s = (v[p] >= 1.0f);
            unsigned long long mk = __ballot(s);
            if (s) v[p] = 0.f;
            if (lane == 0) s1m[base + p] = mk;
        }
    }
}

// ---------------- conv2 MFMA v6: 512-thread block, M-tile 256, full-halo Aexp,
// tap-granular double-buffered B prefetch (1 barrier/tap). Order tap->ks->split
// (bit-identical to the r3 kernel). LDS 145KB -> 1 block/CU (gfx950: 160KB/CU).
__global__ __launch_bounds__(512, 2) void conv2_mfma(
    const unsigned long long* __restrict__ s1m,   // [8][128][1024]
    const unsigned short* __restrict__ w2s,
    const float* __restrict__ g, const float* __restrict__ bb,
    const float* __restrict__ mm, const float* __restrict__ vv,
    unsigned long long* __restrict__ s2pm)        // [8][128][256][2]
{
    __shared__ unsigned long long mt[2][340];      // 5440 B  (10x34 halo, dbuf)
    __shared__ unsigned short Aexp[340 * 64];      // 43520 B
    __shared__ unsigned short Bt[2][3 * 8192];     // 98304 B (dbuf x 3 splits x 16KB)
    __shared__ unsigned short pm16[4][16][8];      // 1024 B

    int tid = threadIdx.x;
    int m0 = blockIdx.x << 8;        // 256 rows per block; 512 blocks
    int b = m0 >> 10;
    int pix0 = m0 & 1023;            // 0,256,512,768
    int y0 = pix0 >> 5;              // 0,8,16,24

    int w = tid >> 6, lane = tid & 63;
    int wm = w & 3, wn = w >> 2;     // 8 waves: 4 m-quarters x 2 n-halves
    int q = lane >> 4, r = lane & 15;
    int swr = r & 7;

    int yloc[4], xloc[4];
#pragma unroll
    for (int i = 0; i < 4; ++i) {
        int mrow = wm * 64 + i * 16 + r;
        yloc[i] = mrow >> 5; xloc[i] = mrow & 31;
    }

    float scl[4], bia[4];
#pragma unroll
    for (int j = 0; j < 4; ++j) {
        int oc = wn * 64 + j * 16 + r;
        float s0 = g[oc] / sqrtf(vv[oc] + EPS);
        scl[j] = s0;
        bia[j] = bb[oc] - mm[oc] * s0;
    }

    float vr[4][4][4];
#pragma unroll
    for (int i = 0; i < 4; ++i)
#pragma unroll
        for (int j = 0; j < 4; ++j)
#pragma unroll
            for (int k = 0; k < 4; ++k) vr[i][j][k] = 0.f;

    const char* w2sb = (const char*)w2s;
    char* Btb = (char*)Bt;

    // prologue: stage mt[0]; prefetch tap0 B (all 3 splits) into Bt[0]
    for (int i = tid; i < 340; i += 512) {
        int ly = i / 34, lx = i % 34;
        int yy = y0 + ly - 1, xx = lx - 1;
        unsigned long long mv = 0ULL;
        if (yy >= 0 && yy < 32 && xx >= 0 && xx < 32)
            mv = s1m[(b << 10) + (yy << 5) + xx];
        mt[0][i] = mv;
    }
#pragma unroll
    for (int s = 0; s < 3; ++s)
#pragma unroll
        for (int p = 0; p < 2; ++p)
            gl_lds16(w2sb + s * 147456 + p * 8192 + (w << 10) + (lane << 4),
                     Btb + s * 16384 + p * 8192 + (w << 10));
    __syncthreads();

    int pp = 0;
    for (int t = 0; t < 8; ++t) {
        {   // expand whole halo to bf16 once per t
            const unsigned long long* mtc = mt[t & 1];
            for (int u = tid; u < 680; u += 512) {
                int p = u >> 1, hc = u & 1;
                unsigned long long mk = mtc[p];
                unsigned int w32 = (unsigned int)(mk >> (hc << 5));
#pragma unroll
                for (int c4 = 0; c4 < 4; ++c4) {
                    int c = (hc << 2) + c4;
                    *(uint4*)((char*)Aexp + p * 128 + ((c ^ (p & 7)) << 4)) =
                        expand8(w32 >> (c4 << 3));
                }
            }
        }
        if (t < 7) {
            for (int i = tid; i < 340; i += 512) {
                int ly = i / 34, lx = i % 34;
                int yy = y0 + ly - 1, xx = lx - 1;
                unsigned long long mv = 0ULL;
                if (yy >= 0 && yy < 32 && xx >= 0 && xx < 32)
                    mv = s1m[(size_t)(t + 1) * 131072 + (b << 10) + (yy << 5) + xx];
                mt[(t + 1) & 1][i] = mv;
            }
        }
        __syncthreads();

        f32x4 acc[4][4];
#pragma unroll
        for (int i = 0; i < 4; ++i)
#pragma unroll
            for (int j = 0; j < 4; ++j) acc[i][j] = (f32x4){0.f, 0.f, 0.f, 0.f};

        for (int tap = 0; tap < 9; ++tap) {
            int dy = tap / 3, dx = tap - dy * 3;
            {   // prefetch next tap's B (all 3 splits) into the other buffer
                int tap2 = (tap == 8) ? 0 : (tap + 1);
                const char* gb = w2sb + tap2 * 16384 + (w << 10) + (lane << 4);
                char* lb = Btb + (pp ^ 1) * 49152 + (w << 10);
#pragma unroll
                for (int s = 0; s < 3; ++s)
#pragma unroll
                    for (int p = 0; p < 2; ++p)
                        gl_lds16(gb + s * 147456 + p * 8192, lb + s * 16384 + p * 8192);
            }
            const char* Bc = Btb + pp * 49152;
#pragma unroll
            for (int ks = 0; ks < 2; ++ks) {
                bf16x8 af[4];
#pragma unroll
                for (int i = 0; i < 4; ++i) {
                    int p3 = (yloc[i] + dy) * 34 + xloc[i] + dx;
                    af[i] = *(const bf16x8*)((const char*)Aexp + p3 * 128 +
                             ((((ks << 2) + q) ^ (p3 & 7)) << 4));
                }
#pragma unroll
                for (int s = 0; s < 3; ++s) {
                    bf16x8 bfr[4];
#pragma unroll
                    for (int j = 0; j < 4; ++j)
                        bfr[j] = *(const bf16x8*)(Bc + s * 16384 + (wn * 64 + j * 16 + r) * 128 +
                                 ((((ks << 2) + q) ^ swr) << 4));
#pragma unroll
                    for (int i = 0; i < 4; ++i)
#pragma unroll
                        for (int j = 0; j < 4; ++j)
                            acc[i][j] = __builtin_amdgcn_mfma_f32_16x16x32_bf16(af[i], bfr[j], acc[i][j], 0, 0, 0);
                }
            }
            __syncthreads();
            pp ^= 1;
        }

        // epilogue: BN + LIF (v in regs) + 2x2 pool + bitpack
        unsigned long long S = 0ULL;
#pragma unroll
        for (int i = 0; i < 4; ++i)
#pragma unroll
            for (int j = 0; j < 4; ++j)
#pragma unroll
                for (int reg = 0; reg < 4; ++reg) {
                    float pre = acc[i][j][reg] * scl[j] + bia[j];
                    float vo = vr[i][j][reg];
                    vo = vo + (pre - vo) * 0.5f;
                    bool sp = (vo >= 1.0f);
                    vr[i][j][reg] = sp ? 0.f : vo;
                    if (sp) S |= 1ULL << (i * 16 + j * 4 + reg);
                }
#pragma unroll
        for (int b1 = 0; b1 < 2; ++b1)
#pragma unroll
            for (int u = 0; u < 2; ++u)
#pragma unroll
                for (int j = 0; j < 4; ++j) {
                    int k0 = b1 * 16 + j * 4 + 2 * u;
                    bool sp = (((S >> k0) | (S >> (k0 + 1)) | (S >> (k0 + 32)) | (S >> (k0 + 33))) & 1ULL) != 0;
                    unsigned long long mk = __ballot(sp);
                    if (r == 0)
                        pm16[wm][b1 * 8 + (q << 1) + u][wn * 4 + j] = (unsigned short)(mk >> (q << 4));
                }
        __syncthreads();
        if (tid < 128) {
            int py = tid >> 5, px = (tid >> 1) & 15, h = tid & 1;
            unsigned long long vmk = *(unsigned long long*)&pm16[py][px][h << 2];
            s2pm[(size_t)t * 65536 + ((size_t)(b << 8) + ((y0 >> 1) + py) * 16 + px) * 2 + h] = vmk;
        }
    }
}

// ---------------- conv3 MFMA v6: 512-thread block, whole 16x16 image per block,
// per-half full-halo Aexp, tap-granular dbuf B prefetch. 256 blocks (1/CU).
__global__ __launch_bounds__(512, 2) void conv3_mfma(
    const unsigned long long* __restrict__ s2pm,  // [8][128][256][2]
    const unsigned short* __restrict__ w3s,
    const float* __restrict__ g, const float* __restrict__ bb,
    const float* __restrict__ mm, const float* __restrict__ vv,
    unsigned short* __restrict__ s3)              // [8][128][16384] bf16, swizzled
{
    __shared__ unsigned long long mt3[2][324][2];  // 10368 B (18x18 halo x 2 halves, dbuf)
    __shared__ unsigned short Aexp[324 * 64];      // 41472 B
    __shared__ unsigned short Bt[2][3 * 8192];     // 98304 B

    int tid = threadIdx.x;
    int b = blockIdx.x;
    int n0 = blockIdx.y << 7;

    int w = tid >> 6, lane = tid & 63;
    int wm = w & 3, wn = w >> 2;
    int q = lane >> 4, r = lane & 15;
    int swr = r & 7;

    float scl[4], bia[4];
#pragma unroll
    for (int j = 0; j < 4; ++j) {
        int oc = n0 + wn * 64 + j * 16 + r;
        float s0 = g[oc] / sqrtf(vv[oc] + EPS);
        scl[j] = s0;
        bia[j] = bb[oc] - mm[oc] * s0;
    }

    float vr[4][4][4];
#pragma unroll
    for (int i = 0; i < 4; ++i)
#pragma unroll
        for (int j = 0; j < 4; ++j)
#pragma unroll
            for (int k = 0; k < 4; ++k) vr[i][j][k] = 0.f;

    const char* w3sb = (const char*)w3s;
    char* Btb = (char*)Bt;
    int bsw = b & 7;

    // prologue: stage mt3[0]; prefetch cc=0 B into Bt[0]
    for (int i = tid; i < 648; i += 512) {
        int p = i >> 1, hh = i & 1;
        int ly = p / 18, lx = p % 18;
        int yy = ly - 1, xx = lx - 1;
        unsigned long long mv = 0ULL;
        if (yy >= 0 && yy < 16 && xx >= 0 && xx < 16)
            mv = s2pm[((size_t)(b << 8) + (yy << 4) + xx) * 2 + hh];
        mt3[0][p][hh] = mv;
    }
#pragma unroll
    for (int s = 0; s < 3; ++s)
#pragma unroll
        for (int p = 0; p < 2; ++p)
            gl_lds16(w3sb + s * 589824 + n0 * 128 + p * 8192 + (w << 10) + (lane << 4),
                     Btb + s * 16384 + p * 8192 + (w << 10));
    __syncthreads();

    int pp = 0;
    for (int t = 0; t < 8; ++t) {
        {   // expand halo, ic-half 0
            for (int u = tid; u < 648; u += 512) {
                int p = u >> 1, hc = u & 1;
                unsigned long long mk = mt3[t & 1][p][0];
                unsigned int w32 = (unsigned int)(mk >> (hc << 5));
#pragma unroll
                for (int c4 = 0; c4 < 4; ++c4) {
                    int c = (hc << 2) + c4;
                    *(uint4*)((char*)Aexp + p * 128 + ((c ^ (p & 7)) << 4)) =
                        expand8(w32 >> (c4 << 3));
                }
            }
        }
        if (t < 7) {
            for (int i = tid; i < 648; i += 512) {
                int p = i >> 1, hh = i & 1;
                int ly = p / 18, lx = p % 18;
                int yy = ly - 1, xx = lx - 1;
                unsigned long long mv = 0ULL;
                if (yy >= 0 && yy < 16 && xx >= 0 && xx < 16)
                    mv = s2pm[(size_t)(t + 1) * 65536 + ((size_t)(b << 8) + (yy << 4) + xx) * 2 + hh];
                mt3[(t + 1) & 1][p][hh] = mv;
            }
        }
        __syncthreads();

        f32x4 acc[4][4];
#pragma unroll
        for (int i = 0; i < 4; ++i)
#pragma unroll
            for (int j = 0; j < 4; ++j) acc[i][j] = (f32x4){0.f, 0.f, 0.f, 0.f};

        for (int h = 0; h < 2; ++h) {
            for (int tap = 0; tap < 9; ++tap) {
                int dy = tap / 3, dx = tap - dy * 3;
                int cc = tap * 2 + h;
                {   // prefetch next (h,tap) B
                    int ncc = (tap < 8) ? (cc + 2) : ((h == 0) ? 1 : 0);
                    const char* gb = w3sb + ncc * 32768 + n0 * 128 + (w << 10) + (lane << 4);
                    char* lb = Btb + (pp ^ 1) * 49152 + (w << 10);
#pragma unroll
                    for (int s = 0; s < 3; ++s)
#pragma unroll
                        for (int p = 0; p < 2; ++p)
                            gl_lds16(gb + s * 589824 + p * 8192, lb + s * 16384 + p * 8192);
                }
                const char* Bc = Btb + pp * 49152;
#pragma unroll
                for (int ks = 0; ks < 2; ++ks) {
                    bf16x8 af[4];
#pragma unroll
                    for (int i = 0; i < 4; ++i) {
                        int p3 = (wm * 4 + i + dy) * 18 + r + dx;
                        af[i] = *(const bf16x8*)((const char*)Aexp + p3 * 128 +
                                 ((((ks << 2) + q) ^ (p3 & 7)) << 4));
                    }
#pragma unroll
                    for (int s = 0; s < 3; ++s) {
                        bf16x8 bfr[4];
#pragma unroll
                        for (int j = 0; j < 4; ++j)
                            bfr[j] = *(const bf16x8*)(Bc + s * 16384 + (wn * 64 + j * 16 + r) * 128 +
                                     ((((ks << 2) + q) ^ swr) << 4));
#pragma unroll
                        for (int i = 0; i < 4; ++i)
#pragma unroll
                            for (int j = 0; j < 4; ++j)
                                acc[i][j] = __builtin_amdgcn_mfma_f32_16x16x32_bf16(af[i], bfr[j], acc[i][j], 0, 0, 0);
                    }
                }
                __syncthreads();
                pp ^= 1;
            }
            if (h == 0) {   // rebuild Aexp for ic-half 1
                for (int u = tid; u < 648; u += 512) {
                    int p = u >> 1, hc = u & 1;
                    unsigned long long mk = mt3[t & 1][p][1];
                    unsigned int w32 = (unsigned int)(mk >> (hc << 5));
#pragma unroll
                    for (int c4 = 0; c4 < 4; ++c4) {
                        int c = (hc << 2) + c4;
                        *(uint4*)((char*)Aexp + p * 128 + ((c ^ (p & 7)) << 4)) =
                            expand8(w32 >> (c4 << 3));
                    }
                }
                __syncthreads();
            }
        }

        // epilogue: BN + LIF + pool -> bf16 spikes
        unsigned long long S = 0ULL;
#pragma unroll
        for (int i = 0; i < 4; ++i)
#pragma unroll
            for (int j = 0; j < 4; ++j)
#pragma unroll
                for (int reg = 0; reg < 4; ++reg) {
                    float pre = acc[i][j][reg] * scl[j] + bia[j];
                    float vo = vr[i][j][reg];
                    vo = vo + (pre - vo) * 0.5f;
                    bool sp = (vo >= 1.0f);
                    vr[i][j][reg] = sp ? 0.f : vo;
                    if (sp) S |= 1ULL << (i * 16 + j * 4 + reg);
                }
        unsigned short* s3t = s3 + (size_t)t * 2097152;
#pragma unroll
        for (int a2 = 0; a2 < 2; ++a2)
#pragma unroll
            for (int u = 0; u < 2; ++u)
#pragma unroll
                for (int j = 0; j < 4; ++j) {
                    int kA = 32 * a2 + j * 4 + 2 * u;
                    bool sp = (((S >> kA) | (S >> (kA + 1)) | (S >> (kA + 16)) | (S >> (kA + 17))) & 1ULL) != 0;
                    int oc = n0 + wn * 64 + j * 16 + r;
                    int y2 = wm * 2 + a2;
                    int x2 = (q << 1) + u;
                    s3t[(size_t)(b << 14) + oc * 64 + ((y2 ^ bsw) << 3) + x2] =
                        (unsigned short)(sp ? 0x3F80 : 0);
                }
    }
}

// ---------------- FC MFMA GEMM, split-K into 8 deterministic partials ----------------
__global__ __launch_bounds__(256, 2) void fc_mfma(
    const unsigned short* __restrict__ s3,    // [1024][16384] bf16, swizzled by (m&7)
    const unsigned short* __restrict__ fcs,
    float* __restrict__ pre4p)                // [8][1024][512]
{
    __shared__ unsigned short A[128 * 64];
    __shared__ unsigned short B[3 * 128 * 64];

    int tid = threadIdx.x;
    int m0 = blockIdx.x << 7;
    int n0 = blockIdx.y << 7;
    int kseg = blockIdx.z;
    int cc0 = kseg << 5;

    int w = tid >> 6, lane = tid & 63;
    int wm = w & 1, wn = w >> 1;
    int q = lane >> 4, r = lane & 15;
    int swr = r & 7;

    f32x4 acc[4][4];
#pragma unroll
    for (int i = 0; i < 4; ++i)
#pragma unroll
        for (int j = 0; j < 4; ++j) acc[i][j] = (f32x4){0.f, 0.f, 0.f, 0.f};

    const char* s3b = (const char*)s3;
    const char* fcsb = (const char*)fcs;

    for (int cc = cc0; cc < cc0 + 32; ++cc) {
        __syncthreads();
        {
            char* lb = (char*)A + (w << 12);
#pragma unroll
            for (int p = 0; p < 4; ++p)
                gl_lds16(s3b + (size_t)(m0 + w * 32 + p * 8 + (lane >> 3)) * 32768
                             + cc * 128 + ((lane & 7) << 4),
                         lb + (p << 10));
        }
        {
            const char* gb = fcsb + cc * 65536 + n0 * 128 + (w << 12) + (lane << 4);
            char* lb = (char*)B + (w << 12);
#pragma unroll
            for (int s = 0; s < 3; ++s)
#pragma unroll
                for (int p = 0; p < 4; ++p)
                    gl_lds16(gb + s * 16777216 + (p << 10), lb + s * 16384 + (p << 10));
        }
        __syncthreads();
#pragma unroll
        for (int ks = 0; ks < 2; ++ks) {
            bf16x8 af[4];
#pragma unroll
            for (int i = 0; i < 4; ++i)
                af[i] = *(const bf16x8*)((const char*)A + (wm * 64 + i * 16 + r) * 128 + ((((ks << 2) + q) ^ swr) << 4));
#pragma unroll
            for (int s = 0; s < 3; ++s) {
                bf16x8 bfr[4];
#pragma unroll
                for (int j = 0; j < 4; ++j)
                    bfr[j] = *(const bf16x8*)((const char*)B + s * 16384 + (wn * 64 + j * 16 + r) * 128 + ((((ks << 2) + q) ^ swr) << 4));
#pragma unroll
                for (int i = 0; i < 4; ++i)
#pragma unroll
                    for (int j = 0; j < 4; ++j)
                        acc[i][j] = __builtin_amdgcn_mfma_f32_16x16x32_bf16(af[i], bfr[j], acc[i][j], 0, 0, 0);
            }
        }
    }
#pragma unroll
    for (int i = 0; i < 4; ++i) {
#pragma unroll
        for (int j = 0; j < 4; ++j) {
            size_t base = ((size_t)kseg * 1024 + m0 + wm * 64 + i * 16 + (q << 2)) * 512
                        + n0 + wn * 64 + j * 16 + r;
#pragma unroll
            for (int reg = 0; reg < 4; ++reg)
                pre4p[base + (size_t)reg * 512] = acc[i][j][reg];
        }
    }
}

// ---------------- LIF over FC output (sum 8 partials deterministically) + mean ----------------
__global__ void lif4_mean(const float* __restrict__ P, float* __restrict__ feat) {
    int i = blockIdx.x * 256 + threadIdx.x;
    if (i >= 65536) return;
    int b = i >> 9, f = i & 511;
    float v = 0.f, sum = 0.f;
#pragma unroll
    for (int t = 0; t < 8; ++t) {
        float pre = 0.f;
#pragma unroll
        for (int s = 0; s < 8; ++s)
            pre += P[(size_t)s * 524288 + (size_t)(t * 128 + b) * 512 + f];
        v = v + (pre - v) * 0.5f;
        if (v >= 1.0f) { sum += 1.f; v = 0.f; }
    }
    feat[i] = sum * 0.125f;
}

__global__ void protos_norm(const float* __restrict__ P, float* __restrict__ pn) {
    int p = blockIdx.x;
    int lane = threadIdx.x;
    float ss = 0.f;
    for (int f = lane; f < 512; f += 64) { float x = P[p * 512 + f]; ss += x * x; }
#pragma unroll
    for (int o = 32; o > 0; o >>= 1) ss += __shfl_xor(ss, o);
    float inv = 1.f / fmaxf(sqrtf(ss), 1e-12f);
    for (int f = lane; f < 512; f += 64) pn[p * 512 + f] = P[p * 512 + f] * inv;
}

__global__ void final_logits(const float* __restrict__ feat, const float* __restrict__ pn,
                             float* __restrict__ out) {
    int b = blockIdx.x;
    int lane = threadIdx.x;
    float fr[8];
    float ss = 0.f;
#pragma unroll
    for (int j = 0; j < 8; ++j) { fr[j] = feat[b * 512 + j * 64 + lane]; ss += fr[j] * fr[j]; }
#pragma unroll
    for (int o = 32; o > 0; o >>= 1) ss += __shfl_xor(ss, o);
    float inv = 10.f / fmaxf(sqrtf(ss), 1e-12f);
    for (int p = 0; p < 10; ++p) {
        float d = 0.f;
#pragma unroll
        for (int j = 0; j < 8; ++j) d += fr[j] * pn[p * 512 + j * 64 + lane];
#pragma unroll
        for (int o = 32; o > 0; o >>= 1) d += __shfl_xor(d, o);
        if (lane == 0) out[b * 10 + p] = d * inv;
    }
}

extern "C" void kernel_launch(void* const* d_in, const int* in_sizes, int n_in,
                              void* d_out, int out_size, void* d_ws, size_t ws_size,
                              hipStream_t stream) {
    const float* x      = (const float*)d_in[0];
    const float* w1     = (const float*)d_in[1];
    const float* w2     = (const float*)d_in[2];
    const float* w3     = (const float*)d_in[3];
    const float* fc1    = (const float*)d_in[4];
    const float* protos = (const float*)d_in[5];
    const float* g1 = (const float*)d_in[6],  *b1 = (const float*)d_in[7];
    const float* m1 = (const float*)d_in[8],  *v1 = (const float*)d_in[9];
    const float* g2 = (const float*)d_in[10], *b2 = (const float*)d_in[11];
    const float* m2 = (const float*)d_in[12], *v2p = (const float*)d_in[13];
    const float* g3 = (const float*)d_in[14], *b3 = (const float*)d_in[15];
    const float* m3 = (const float*)d_in[16], *v3p = (const float*)d_in[17];

    char* ws = (char*)d_ws;
    unsigned short* w2s = (unsigned short*)(ws + OFF_W2S);
    unsigned short* w3s = (unsigned short*)(ws + OFF_W3S);
    unsigned short* fcs = (unsigned short*)(ws + OFF_FCS);
    unsigned long long* s1m  = (unsigned long long*)(ws + OFF_S1M);
    unsigned long long* s2pm = (unsigned long long*)(ws + OFF_S2PM);
    unsigned short* s3 = (unsigned short*)(ws + OFF_S3);
    float* pre4p = (float*)(ws + OFF_PRE4P);
    float* feat  = (float*)(ws + OFF_FEAT);
    float* pn    = (float*)(ws + OFF_PN);

    repack_w2s<<<288, 256, 0, stream>>>(w2, w2s);
    repack_w3s<<<1152, 256, 0, stream>>>(w3, w3s);
    repack_fcs<<<32768, 256, 0, stream>>>(fc1, fcs);

    conv1_lif_pack<<<4096, 256, 0, stream>>>(x, w1, g1, b1, m1, v1, s1m);
    conv2_mfma<<<512, 512, 0, stream>>>(s1m, w2s, g2, b2, m2, v2p, s2pm);
    conv3_mfma<<<dim3(128, 2), 512, 0, stream>>>(s2pm, w3s, g3, b3, m3, v3p, s3);

    fc_mfma<<<dim3(8, 4, 8), 256, 0, stream>>>(s3, fcs, pre4p);
    lif4_mean<<<256, 256, 0, stream>>>(pre4p, feat);
    protos_norm<<<10, 64, 0, stream>>>(protos, pn);
    final_logits<<<128, 64, 0, stream>>>(feat, pn, (float*)d_out);
}